// Round 7
// baseline (230.697 us; speedup 1.0000x reference)
//
#include <hip/hip_runtime.h>
#include <hip/hip_bf16.h>
#include <math.h>

// Problem constants
#define BATCH 8
#define SEQ   2048
#define CH    512
#define ROWS  (BATCH * SEQ)   // 16384
#define INVSQ 0.044194173824159216f  // 1/sqrt(512)

#define TP 68                  // transpose-tile pitch (2-way conflict = free)

typedef __attribute__((ext_vector_type(8))) __bf16 bf16x8;
typedef __attribute__((ext_vector_type(4))) float f32x4;

__device__ inline unsigned short f2bf(float f) {
    unsigned u = __builtin_bit_cast(unsigned, f);
    u += 0x7fffu + ((u >> 16) & 1u);   // round-to-nearest-even
    return (unsigned short)(u >> 16);
}
__device__ inline float bf2f(unsigned short s) {
    unsigned u = ((unsigned)s) << 16;
    return __builtin_bit_cast(float, u);
}

// ---------------------------------------------------------------------------
// fuse_x: x fp32 [16384,512] -> out[:, :, 0:512] (fp32) AND xb (bf16).
// Also zeroes Z (blocks 0..63).
// ---------------------------------------------------------------------------
__global__ __launch_bounds__(256) void fuse_x_kernel(
    const float* __restrict__ x, unsigned short* __restrict__ xb,
    float* __restrict__ out, float* __restrict__ Z)
{
    if (blockIdx.x < 64) Z[blockIdx.x * 256 + threadIdx.x] = 0.f;
    size_t base = ((size_t)blockIdx.x * 256 + threadIdx.x) * 8;
    size_t row = base >> 9, c = base & 511;
    float4 v0 = *(const float4*)(x + base);
    float4 v1 = *(const float4*)(x + base + 4);
    float* o = out + row * 1024 + c;
    *(float4*)o = v0;
    *(float4*)(o + 4) = v1;
    alignas(16) unsigned short t[8];
    t[0] = f2bf(v0.x); t[1] = f2bf(v0.y); t[2] = f2bf(v0.z); t[3] = f2bf(v0.w);
    t[4] = f2bf(v1.x); t[5] = f2bf(v1.y); t[6] = f2bf(v1.z); t[7] = f2bf(v1.w);
    *(uint4*)(xb + base) = *(const uint4*)t;
}

// ---------------------------------------------------------------------------
// transpose_w: W fp32 [512 k][512 n] -> Wt bf16 [3][512 n][512 k]
// ---------------------------------------------------------------------------
__global__ __launch_bounds__(256) void transpose_w_kernel(
    const float* __restrict__ Wq, const float* __restrict__ Wk,
    const float* __restrict__ Wv, unsigned short* __restrict__ Wt)
{
    __shared__ unsigned short T[64 * TP];
    const int k0 = blockIdx.x * 64, n0 = blockIdx.y * 64, w = blockIdx.z;
    const float* W = (w == 0) ? Wq : (w == 1) ? Wk : Wv;
    const int tid = threadIdx.x;
#pragma unroll
    for (int i = 0; i < 2; ++i) {
        int slot = tid + i * 256;
        int kr = slot >> 3, c8 = (slot & 7) << 3;
        float4 a = *(const float4*)(W + (size_t)(k0 + kr) * CH + n0 + c8);
        float4 b = *(const float4*)(W + (size_t)(k0 + kr) * CH + n0 + c8 + 4);
        T[(c8 + 0) * TP + kr] = f2bf(a.x); T[(c8 + 1) * TP + kr] = f2bf(a.y);
        T[(c8 + 2) * TP + kr] = f2bf(a.z); T[(c8 + 3) * TP + kr] = f2bf(a.w);
        T[(c8 + 4) * TP + kr] = f2bf(b.x); T[(c8 + 5) * TP + kr] = f2bf(b.y);
        T[(c8 + 6) * TP + kr] = f2bf(b.z); T[(c8 + 7) * TP + kr] = f2bf(b.w);
    }
    __syncthreads();
#pragma unroll
    for (int i = 0; i < 2; ++i) {
        int slot = tid + i * 256;
        int nr = slot >> 3, k8 = (slot & 7) << 3;
        uint2 lo = *(const uint2*)(T + nr * TP + k8);
        uint2 hi = *(const uint2*)(T + nr * TP + k8 + 4);
        uint4 u; u.x = lo.x; u.y = lo.y; u.z = hi.x; u.w = hi.y;
        *(uint4*)(Wt + ((size_t)w * CH + n0 + nr) * CH + k0 + k8) = u;
    }
}

// ---------------------------------------------------------------------------
// transpose_v: vb bf16 [b][s][v] -> Vt bf16 [b][v][s], scaled by 1/Z[b][s].
// ---------------------------------------------------------------------------
__global__ __launch_bounds__(256) void transpose_v_kernel(
    const unsigned short* __restrict__ vb, const float* __restrict__ Z,
    unsigned short* __restrict__ Vt)
{
    __shared__ unsigned short T[64 * TP];
    const int s0 = blockIdx.x * 64, v0 = blockIdx.y * 64, b = blockIdx.z;
    const int tid = threadIdx.x;
#pragma unroll
    for (int i = 0; i < 2; ++i) {
        int slot = tid + i * 256;
        int sr = slot >> 3, c8 = (slot & 7) << 3;
        float inv = 1.0f / Z[b * SEQ + s0 + sr];
        uint4 raw = *(const uint4*)(vb + ((size_t)b * SEQ + s0 + sr) * CH + v0 + c8);
        const unsigned short* p = (const unsigned short*)&raw;
#pragma unroll
        for (int j = 0; j < 8; ++j)
            T[(c8 + j) * TP + sr] = f2bf(bf2f(p[j]) * inv);
    }
    __syncthreads();
#pragma unroll
    for (int i = 0; i < 2; ++i) {
        int slot = tid + i * 256;
        int vr = slot >> 3, s8 = (slot & 7) << 3;
        uint2 lo = *(const uint2*)(T + vr * TP + s8);
        uint2 hi = *(const uint2*)(T + vr * TP + s8 + 4);
        uint4 u; u.x = lo.x; u.y = lo.y; u.z = hi.x; u.w = hi.y;
        *(uint4*)(Vt + ((size_t)b * CH + v0 + vr) * SEQ + s0 + s8) = u;
    }
}

// ===========================================================================
// 256x256-tile BK=64 8-wave 4-phase pipeline (m201-style), 512 thr.
// LDS 128 KB: A[2][256][64] | B[2][256][64] bf16 (128-B rows).
// Waves: waveA = wave>>2 (0..1) -> A-strip 128 rows; waveB = wave&3 (0..3)
// -> B-strip 64 rows. Per-wave output 128x64 = acc[8][4].
// Swizzle (both sides, involution slot^=(row&7) on 16-B slots): stage keeps
// LDS linear with pre-swizzled global source col; reads use s80/s81.
// Per K-tile U, 4 phases of 16 MFMA:
//  P1: stageA(U+1) | read b[0-3] h0,h1 (8) + a[0-1] h0,h1 (4) | bar |
//      lgkm(0) | MFMA r0-1 | bar
//  P2: stageB(U+1) | read a[2-3] | bar | lgkm(0) | MFMA r2-3 | bar
//  P3: read a[4-5] | bar | lgkm(0) | MFMA r4-5 | bar
//  P4: read a[6-7] | bar | lgkm(0) | MFMA r6-7 | vmcnt(0) | bar
// Invariants: stageX(U+1) targets buf (U+1)&1, last read in tile U-1 and
// protected by U-1's closing barrier (WAR). Tile U's data was staged in
// U-1 (A at P1, B at P2) and drained by U-1's vmcnt(0)+barrier (RAW,
// cross-wave publish). Drain cover >= 2-3 phases (~1200-1800 cyc) > HBM
// latency, so vmcnt(0) is cheap here.
// ===========================================================================
#define STAGE4(gsrc, dslab)                                                   \
    _Pragma("unroll")                                                         \
    for (int p = 0; p < 4; ++p)                                               \
        __builtin_amdgcn_global_load_lds(                                     \
            (const __attribute__((address_space(1))) unsigned int*)((gsrc) + (size_t)p * 64 * gstride), \
            (__attribute__((address_space(3))) unsigned int*)((dslab) + p * 4096 + (tid << 3)), \
            16, 0, 0);

#define RD_A(rb)                                                              \
    a00 = *(const bf16x8*)(Ab + (arow + (rb)     * 16) * 64 + s80);           \
    a01 = *(const bf16x8*)(Ab + (arow + (rb)     * 16) * 64 + s81);           \
    a10 = *(const bf16x8*)(Ab + (arow + (rb + 1) * 16) * 64 + s80);           \
    a11 = *(const bf16x8*)(Ab + (arow + (rb + 1) * 16) * 64 + s81);

#define MFMA_PAIR(rb)                                                         \
    __builtin_amdgcn_s_setprio(1);                                            \
    _Pragma("unroll")                                                         \
    for (int cc = 0; cc < 4; ++cc)                                            \
        acc[rb][cc] = __builtin_amdgcn_mfma_f32_16x16x32_bf16(a00, b0[cc], acc[rb][cc], 0, 0, 0); \
    _Pragma("unroll")                                                         \
    for (int cc = 0; cc < 4; ++cc)                                            \
        acc[(rb) + 1][cc] = __builtin_amdgcn_mfma_f32_16x16x32_bf16(a10, b0[cc], acc[(rb) + 1][cc], 0, 0, 0); \
    _Pragma("unroll")                                                         \
    for (int cc = 0; cc < 4; ++cc)                                            \
        acc[rb][cc] = __builtin_amdgcn_mfma_f32_16x16x32_bf16(a01, b1[cc], acc[rb][cc], 0, 0, 0); \
    _Pragma("unroll")                                                         \
    for (int cc = 0; cc < 4; ++cc)                                            \
        acc[(rb) + 1][cc] = __builtin_amdgcn_mfma_f32_16x16x32_bf16(a11, b1[cc], acc[(rb) + 1][cc], 0, 0, 0); \
    __builtin_amdgcn_s_setprio(0);

#define BAR_LGKM                                                              \
    __builtin_amdgcn_s_barrier();                                             \
    asm volatile("s_waitcnt lgkmcnt(0)" ::: "memory");                        \
    __builtin_amdgcn_sched_barrier(0);

#define PIPE256(NT)                                                           \
    stageA(0); stageB(0);                                                     \
    asm volatile("s_waitcnt vmcnt(0)" ::: "memory");                          \
    __builtin_amdgcn_s_barrier();                                             \
    __builtin_amdgcn_sched_barrier(0);                                        \
    _Pragma("unroll")                                                         \
    for (int U = 0; U < (NT); ++U) {                                          \
        const unsigned short* Ab = lds + (U & 1) * 16384;                     \
        const unsigned short* Bb = lds + 32768 + (U & 1) * 16384;             \
        bf16x8 b0[4], b1[4], a00, a01, a10, a11;                              \
        /* ---- P1 ---- */                                                    \
        stageA(U + 1);                                                        \
        _Pragma("unroll")                                                     \
        for (int n = 0; n < 4; ++n) {                                         \
            b0[n] = *(const bf16x8*)(Bb + (brow + n * 16) * 64 + s80);        \
            b1[n] = *(const bf16x8*)(Bb + (brow + n * 16) * 64 + s81);        \
        }                                                                     \
        RD_A(0)                                                               \
        BAR_LGKM                                                              \
        MFMA_PAIR(0)                                                          \
        __builtin_amdgcn_s_barrier();                                         \
        /* ---- P2 ---- */                                                    \
        stageB(U + 1);                                                        \
        RD_A(2)                                                               \
        BAR_LGKM                                                              \
        MFMA_PAIR(2)                                                          \
        __builtin_amdgcn_s_barrier();                                         \
        /* ---- P3 ---- */                                                    \
        RD_A(4)                                                               \
        BAR_LGKM                                                              \
        MFMA_PAIR(4)                                                          \
        __builtin_amdgcn_s_barrier();                                         \
        /* ---- P4 ---- */                                                    \
        RD_A(6)                                                               \
        BAR_LGKM                                                              \
        MFMA_PAIR(6)                                                          \
        if (U <= (NT) - 2) asm volatile("s_waitcnt vmcnt(0)" ::: "memory");   \
        __builtin_amdgcn_s_barrier();                                         \
        __builtin_amdgcn_sched_barrier(0);                                    \
    }

// ---------------------------------------------------------------------------
// qkv fused GEMM, 256x256: A = Wt rows (256 weight cols of output), B = xb
// rows (256 x rows). K=512, 8 K-tiles. Grid 384 = 64 xt x 6 wt, bijective
// XCD swizzle (384 = 8 x 48).
// ---------------------------------------------------------------------------
__global__ __launch_bounds__(512) void qkv8_kernel(
    const unsigned short* __restrict__ xb, const unsigned short* __restrict__ Wt,
    const float* __restrict__ bq, const float* __restrict__ bk,
    const float* __restrict__ bv, unsigned short* __restrict__ qkv)
{
    __shared__ unsigned short lds[65536];   // 128 KB
    const int tid = threadIdx.x;
    const int lane = tid & 63, wave = tid >> 6;
    const int waveA = wave >> 2;            // 0..1: weight strip (128 rows)
    const int waveB = wave & 3;             // 0..3: x strip (64 rows)
    const int quad = lane >> 4, l16 = lane & 15;

    int id = (int)blockIdx.x;
    id = (id & 7) * 48 + (id >> 3);         // bijective XCD swizzle
    const int xt = id / 6, wt = id - xt * 6;
    const int xrow0 = xt << 8, wrow0 = wt << 8;

    const size_t gstride = CH;
    const unsigned short* __restrict__ Ag = Wt + (size_t)wrow0 * CH;
    const unsigned short* __restrict__ Bg = xb + (size_t)xrow0 * CH;

    const int scol = (((tid & 7) ^ ((tid >> 3) & 7)) << 3);
    const size_t ga = (size_t)(tid >> 3) * gstride + scol;
    const int s80 = ((quad ^ (l16 & 7)) << 3);
    const int s81 = s80 ^ 32;
    const int arow = waveA * 128 + l16;
    const int brow = waveB * 64 + l16;

    f32x4 acc[8][4] = {};

    auto stageA = [&](int V) {
        if (V >= 8) return;
        const unsigned short* g = Ag + ga + V * 64;
        unsigned short* d = lds + (V & 1) * 16384;
        STAGE4(g, d)
    };
    auto stageB = [&](int V) {
        if (V >= 8) return;
        const unsigned short* g = Bg + ga + V * 64;
        unsigned short* d = lds + 32768 + (V & 1) * 16384;
        STAGE4(g, d)
    };

    PIPE256(8)

    const int which = wrow0 >> 9;   // uniform per block
    const float* bias = (which == 0) ? bq : (which == 1) ? bk : bv;
    const float scale = (which == 0) ? INVSQ : 1.0f;
    unsigned short* outw = qkv + (size_t)which * ROWS * CH;
    const int colblk = wrow0 & 511;
#pragma unroll
    for (int r = 0; r < 8; ++r) {
        int colb = colblk + waveA * 128 + r * 16 + quad * 4;
        float4 b4 = *(const float4*)(bias + colb);
#pragma unroll
        for (int c = 0; c < 4; ++c) {
            int m = xrow0 + waveB * 64 + c * 16 + l16;
            alignas(8) unsigned short pk[4];
            pk[0] = f2bf((acc[r][c][0] + b4.x) * scale);
            pk[1] = f2bf((acc[r][c][1] + b4.y) * scale);
            pk[2] = f2bf((acc[r][c][2] + b4.z) * scale);
            pk[3] = f2bf((acc[r][c][3] + b4.w) * scale);
            *(uint2*)(outw + (size_t)m * CH + colb) = *(const uint2*)pk;
        }
    }
}

// ---------------------------------------------------------------------------
// logits, 256x256: C[s][t] = k_s . q_t (q pre-scaled). A = K-tile
// [256 s][512 k], B = Q-tile [256 t][512 k]. Triangle st<=tt over 8x8
// 256-tiles: 36 pairs x 8 batches = 288 blocks, b = blockIdx&7 pins XCD.
// E[t][s] = exp(C) if s<=t else 0; Z[s] via shuffle+atomic.
// Coverage: for t-tile tau256, s-tiles 0..tau256 written -> superset of
// what read consumes; masked entries exact zeros.
// ---------------------------------------------------------------------------
__global__ __launch_bounds__(512) void logits8_kernel(
    const unsigned short* __restrict__ qb, const unsigned short* __restrict__ kb,
    unsigned short* __restrict__ E, float* __restrict__ Z)
{
    __shared__ unsigned short lds[65536];   // 128 KB
    const int tid = threadIdx.x;
    const int lane = tid & 63, wave = tid >> 6;
    const int waveA = wave >> 2;            // 0..1: s strip (128 rows)
    const int waveB = wave & 3;             // 0..3: t strip (64 rows)
    const int quad = lane >> 4, l16 = lane & 15;

    const int b = (int)blockIdx.x & 7;
    const int i = (int)blockIdx.x >> 3;     // 0..35 triangle index
    int tt = (int)((sqrtf(8.f * (float)i + 1.f) - 1.f) * 0.5f);
    int st = i - ((tt * (tt + 1)) >> 1);
    while (st < 0)  { --tt; st = i - ((tt * (tt + 1)) >> 1); }
    while (st > tt) { ++tt; st = i - ((tt * (tt + 1)) >> 1); }
    const int m0s = st << 8;    // s rows (A, from k), 256-wide
    const int n0t = tt << 8;    // t rows (B, from q), 256-wide

    const size_t gstride = CH;
    const unsigned short* __restrict__ Ag = kb + ((size_t)b * SEQ + m0s) * CH;
    const unsigned short* __restrict__ Bg = qb + ((size_t)b * SEQ + n0t) * CH;

    const int scol = (((tid & 7) ^ ((tid >> 3) & 7)) << 3);
    const size_t ga = (size_t)(tid >> 3) * gstride + scol;
    const int s80 = ((quad ^ (l16 & 7)) << 3);
    const int s81 = s80 ^ 32;
    const int arow = waveA * 128 + l16;
    const int brow = waveB * 64 + l16;

    f32x4 acc[8][4] = {};

    auto stageA = [&](int V) {
        if (V >= 8) return;
        const unsigned short* g = Ag + ga + V * 64;
        unsigned short* d = lds + (V & 1) * 16384;
        STAGE4(g, d)
    };
    auto stageB = [&](int V) {
        if (V >= 8) return;
        const unsigned short* g = Bg + ga + V * 64;
        unsigned short* d = lds + 32768 + (V & 1) * 16384;
        STAGE4(g, d)
    };

    PIPE256(8)

    // Epilogue: causal mask, exp, Z partial sums, bf16 E write.
#pragma unroll
    for (int r = 0; r < 8; ++r) {
        int sb = m0s + waveA * 128 + r * 16 + quad * 4;
        float ev[4][4];
#pragma unroll
        for (int c = 0; c < 4; ++c) {
            int t = n0t + waveB * 64 + c * 16 + l16;
#pragma unroll
            for (int reg = 0; reg < 4; ++reg)
                ev[c][reg] = (sb + reg <= t) ? __expf(acc[r][c][reg]) : 0.f;
        }
#pragma unroll
        for (int reg = 0; reg < 4; ++reg) {
            float z = ev[0][reg] + ev[1][reg] + ev[2][reg] + ev[3][reg];
            z += __shfl_xor(z, 1);
            z += __shfl_xor(z, 2);
            z += __shfl_xor(z, 4);
            z += __shfl_xor(z, 8);
            if (l16 == 0) atomicAdd(&Z[b * SEQ + sb + reg], z);
        }
#pragma unroll
        for (int c = 0; c < 4; ++c) {
            int t = n0t + waveB * 64 + c * 16 + l16;
            alignas(8) unsigned short pk[4];
            pk[0] = f2bf(ev[c][0]); pk[1] = f2bf(ev[c][1]);
            pk[2] = f2bf(ev[c][2]); pk[3] = f2bf(ev[c][3]);
            *(uint2*)(E + ((size_t)b * SEQ + t) * SEQ + sb) = *(const uint2*)pk;
        }
    }
}

// ---------------------------------------------------------------------------
// read (unchanged from round 6, passed): C[v][t] = sum_s Vt[v][s] * E[t][s].
// 128x128, BK=64, A 2-buf + B 3-buf (80 KB), single-barrier deep pipeline.
// ---------------------------------------------------------------------------
#define R_STAGE4(gsrc, dslab)                                                 \
    _Pragma("unroll")                                                         \
    for (int p = 0; p < 4; ++p)                                               \
        __builtin_amdgcn_global_load_lds(                                     \
            (const __attribute__((address_space(1))) unsigned int*)((gsrc) + (size_t)p * 32 * gstride), \
            (__attribute__((address_space(3))) unsigned int*)((dslab) + p * 2048 + (tid << 3)), \
            16, 0, 0);

__global__ __launch_bounds__(256, 2) void read8_kernel(
    const unsigned short* __restrict__ E, const unsigned short* __restrict__ Vt,
    float* __restrict__ out)
{
    __shared__ unsigned short lds[40960];   // 80 KB
    const int tid = threadIdx.x;
    const int lane = tid & 63, wave = tid >> 6;
    const int waveA = wave >> 1;            // 0..1: v strip
    const int waveB = wave & 1;             // 0..1: t strip
    const int quad = lane >> 4, l16 = lane & 15;

    const int id = blockIdx.x;
    const int b = id & 7;
    const int rem = id >> 3;
    const int mv = rem & 3;                  // v tile (4)
    const int r0 = rem >> 2;                 // 0..15
    const int tt = (r0 < 8) ? r0 : 23 - r0;  // paired so per-CU work balances
    const int m0v = mv << 7;
    const int n0t = tt << 7;
    const int NT = (tt + 1) * 2;             // K-tiles of 64 (causal extent)

    const size_t gstride = SEQ;
    const unsigned short* __restrict__ Ag = Vt + ((size_t)b * CH + m0v) * SEQ;
    const unsigned short* __restrict__ Bg = E + ((size_t)b * SEQ + n0t) * SEQ;

    const int scol = (((tid & 7) ^ ((tid >> 3) & 7)) << 3);
    const size_t ga = (size_t)(tid >> 3) * gstride + scol;
    const int s80 = ((quad ^ (l16 & 7)) << 3);
    const int s81 = s80 ^ 32;
    const int arow = waveA * 64 + l16;
    const int brow = waveB * 64 + l16;

    f32x4 acc[4][4] = {};

    auto stageA = [&](int V) {
        if (V >= NT) return;
        const unsigned short* g = Ag + ga + V * 64;
        unsigned short* d = lds + (V & 1) * 8192;
        R_STAGE4(g, d)
    };
    auto stageB = [&](int V) {
        if (V >= NT) return;
        const unsigned short* g = Bg + ga + V * 64;
        unsigned short* d = lds + 16384 + (V % 3) * 8192;
        R_STAGE4(g, d)
    };

    stageA(0); stageB(0); stageB(1);
    asm volatile("s_waitcnt vmcnt(4)" ::: "memory");
    __builtin_amdgcn_s_barrier();
    __builtin_amdgcn_sched_barrier(0);

#pragma unroll 2
    for (int U = 0; U < NT; ++U) {
        const unsigned short* Ab = lds + (U & 1) * 8192;
        const unsigned short* Bb = lds + 16384 + (U % 3) * 8192;
        stageA(U + 1);
        stageB(U + 2);
        bf16x8 a0[4], a1[4], c0[4], c1[4];
#pragma unroll
        for (int rr = 0; rr < 4; ++rr) {
            a0[rr] = *(const bf16x8*)(Ab + (arow + rr * 16) * 64 + s80);
            c0[rr] = *(const bf16x8*)(Bb + (brow + rr * 16) * 64 + s80);
        }
        __builtin_amdgcn_sched_barrier(0);
#pragma unroll
        for (int rr = 0; rr < 4; ++rr) {
            a1[rr] = *(const bf16x8*)(Ab + (arow + rr * 16) * 64 + s81);
            c1[rr] = *(const bf16x8*)(Bb + (brow + rr * 16) * 64 + s81);
        }
        asm volatile("s_waitcnt lgkmcnt(8)" ::: "memory");
        __builtin_amdgcn_sched_barrier(0);
        __builtin_amdgcn_s_setprio(1);
#pragma unroll
        for (int rr = 0; rr < 4; ++rr)
#pragma unroll
            for (int cc = 0; cc < 4; ++cc)
                acc[rr][cc] = __builtin_amdgcn_mfma_f32_16x16x32_bf16(
                    a0[rr], c0[cc], acc[rr][cc], 0, 0, 0);
        __builtin_amdgcn_s_setprio(0);
        asm volatile("s_waitcnt lgkmcnt(0)" ::: "memory");
        __builtin_amdgcn_sched_barrier(0);
        __builtin_amdgcn_s_setprio(1);
#pragma unroll
        for (int rr = 0; rr < 4; ++rr)
#pragma unroll
            for (int cc = 0; cc < 4; ++cc)
                acc[rr][cc] = __builtin_amdgcn_mfma_f32_16x16x32_bf16(
                    a1[rr], c1[cc], acc[rr][cc], 0, 0, 0);
        __builtin_amdgcn_s_setprio(0);
        if (U <= NT - 3)      asm volatile("s_waitcnt vmcnt(4)" ::: "memory");
        else if (U == NT - 2) asm volatile("s_waitcnt vmcnt(0)" ::: "memory");
        __builtin_amdgcn_s_barrier();
        __builtin_amdgcn_sched_barrier(0);
    }

#pragma unroll
    for (int r = 0; r < 4; ++r) {
        int v = 512 + m0v + waveA * 64 + r * 16 + quad * 4;
#pragma unroll
        for (int c = 0; c < 4; ++c) {
            int t = n0t + waveB * 64 + c * 16 + l16;
            float4 f;
            f.x = acc[r][c][0]; f.y = acc[r][c][1];
            f.z = acc[r][c][2]; f.w = acc[r][c][3];
            *(float4*)(out + ((size_t)b * SEQ + t) * 1024 + v) = f;
        }
    }
}

extern "C" void kernel_launch(void* const* d_in, const int* in_sizes, int n_in,
                              void* d_out, int out_size, void* d_ws, size_t ws_size,
                              hipStream_t stream) {
    const float* x  = (const float*)d_in[0];
    const float* Wq = (const float*)d_in[1];
    const float* bq = (const float*)d_in[2];
    const float* Wk = (const float*)d_in[3];
    const float* bk = (const float*)d_in[4];
    const float* Wv = (const float*)d_in[5];
    const float* bv = (const float*)d_in[6];
    float* out = (float*)d_out;

    char* ws = (char*)d_ws;
    const size_t QKV_BYTES = (size_t)ROWS * CH * 2;              // 16,777,216
    const size_t E_BYTES   = (size_t)BATCH * SEQ * SEQ * 2;      // 67,108,864
    unsigned short* qkv = (unsigned short*)ws;                   // q,k,v contiguous
    unsigned short* qb = qkv;
    unsigned short* kb = (unsigned short*)(ws + QKV_BYTES);
    unsigned short* vb = (unsigned short*)(ws + 2 * QKV_BYTES);
    unsigned short* E  = (unsigned short*)(ws + 3 * QKV_BYTES);
    float* Z = (float*)(ws + 3 * QKV_BYTES + E_BYTES);
    // Aliases (lifetimes disjoint on the in-order stream):
    unsigned short* xb = E;                                       // dead before logits writes E
    unsigned short* Wt = (unsigned short*)((char*)E + QKV_BYTES); // dead before logits writes E
    unsigned short* Vt = qb;                                      // qb dead after logits

    dim3 blk(256);
    fuse_x_kernel<<<dim3(4096), blk, 0, stream>>>(x, xb, out, Z);
    transpose_w_kernel<<<dim3(8, 8, 3), blk, 0, stream>>>(Wq, Wk, Wv, Wt);
    qkv8_kernel<<<dim3(384), dim3(512), 0, stream>>>(xb, Wt, bq, bk, bv, qkv);
    logits8_kernel<<<dim3(288), dim3(512), 0, stream>>>(qb, kb, E, Z);
    transpose_v_kernel<<<dim3(32, 8, 8), blk, 0, stream>>>(vb, Z, Vt);
    read8_kernel<<<dim3(512), blk, 0, stream>>>(E, Vt, out);
}